// Round 4
// baseline (493.104 us; speedup 1.0000x reference)
//
#include <hip/hip_runtime.h>
#include <hip/hip_bf16.h>
#include <stdint.h>

static constexpr int CI = 16;
static constexpr int CO = 32;
static constexpr int H  = 300000;
static constexpr int K  = 27;
static constexpr float BN_EPS = 1e-5f;

// ---------- bf16 helpers ----------
__device__ __forceinline__ float bf2f(unsigned short u) {
    union { unsigned int i; float f; } v; v.i = ((unsigned int)u) << 16; return v.f;
}
__device__ __forceinline__ unsigned short f2bf(float f) {
    union { float f; unsigned int i; } v; v.f = f;
    unsigned int x = v.i;
    return (unsigned short)((x + 0x7fffu + ((x >> 16) & 1u)) >> 16);  // RNE
}
__device__ __forceinline__ void unpack2(unsigned int u, float& a, float& b) {
    a = bf2f((unsigned short)(u & 0xffffu));
    b = bf2f((unsigned short)(u >> 16));
}

// ---------- kernel 1: x fp32 (CI,H) -> xT bf16 (H,CI) ----------
__global__ __launch_bounds__(256) void prep_x(const float* __restrict__ x,
                                              unsigned short* __restrict__ xT) {
    int h = blockIdx.x * 256 + threadIdx.x;
    if (h >= H) return;
    union { unsigned short s[CI]; uint4 q[2]; } v;
    #pragma unroll
    for (int i = 0; i < CI; ++i) v.s[i] = f2bf(x[(size_t)i * H + h]);  // coalesced per i
    uint4* dst = reinterpret_cast<uint4*>(xT + (size_t)h * CI);
    dst[0] = v.q[0];
    dst[1] = v.q[1];
}

// ---------- kernel 2: weight fp32 (o,i,k) -> fp32 wf[k][o*CI+i] ----------
__global__ __launch_bounds__(256) void prep_w(const float* __restrict__ w,
                                              float* __restrict__ wf) {
    for (int t = threadIdx.x; t < CO * CI * K; t += 256) {
        int k  = t % K;
        int oi = t / K;                 // oi = o*CI + i  (source is (o,i,k) flat)
        wf[k * (CO * CI) + oi] = w[t];
    }
}

// ---------- kernel 3: gathered conv + fused channel sum/sumsq ----------
__global__ __launch_bounds__(256) void conv(const unsigned short* __restrict__ xT,
                                            const float* __restrict__ wf,
                                            const int* __restrict__ neigh,
                                            float* __restrict__ out,
                                            float* __restrict__ gsum,
                                            float* __restrict__ gsq) {
    __shared__ int snb[256 * K];
    const int h = blockIdx.x * 256 + threadIdx.x;

    // stage this block's neighbor indices coalesced into LDS
    {
        const int base = blockIdx.x * 256 * K;
        for (int t = threadIdx.x; t < 256 * K; t += 256) {
            int g = base + t;
            snb[t] = (g < H * K) ? neigh[g] : -1;
        }
    }
    __syncthreads();

    float acc[CO];
    #pragma unroll
    for (int o = 0; o < CO; ++o) acc[o] = 0.f;

    if (h < H) {
        const int* np = &snb[threadIdx.x * K];
        for (int k = 0; k < K; ++k) {
            const int idx = np[k];
            float xi[CI];
            #pragma unroll
            for (int i = 0; i < CI; ++i) xi[i] = 0.f;
            if (idx >= 0) {
                const uint4* p = reinterpret_cast<const uint4*>(xT + (size_t)idx * CI);
                uint4 a = p[0];
                uint4 b = p[1];
                unpack2(a.x, xi[0], xi[1]);   unpack2(a.y, xi[2],  xi[3]);
                unpack2(a.z, xi[4], xi[5]);   unpack2(a.w, xi[6],  xi[7]);
                unpack2(b.x, xi[8], xi[9]);   unpack2(b.y, xi[10], xi[11]);
                unpack2(b.z, xi[12], xi[13]); unpack2(b.w, xi[14], xi[15]);
            }
            const float* wk = wf + k * (CO * CI);   // wave-uniform
            #pragma unroll
            for (int o = 0; o < CO; ++o) {
                float s = acc[o];
                #pragma unroll
                for (int i = 0; i < CI; ++i) s += wk[o * CI + i] * xi[i];
                acc[o] = s;
            }
        }
        #pragma unroll
        for (int o = 0; o < CO; ++o) out[(size_t)o * H + h] = acc[o];  // fp32 out
    }

    // fused BN statistics: 64-lane butterfly per channel, one atomic per wave/channel
    const unsigned lane = threadIdx.x & 63u;
    float mySum = 0.f, mySq = 0.f;
    #pragma unroll
    for (int o = 0; o < CO; ++o) {
        float v = acc[o];
        float q = v * v;
        #pragma unroll
        for (int d = 32; d > 0; d >>= 1) {
            v += __shfl_xor(v, d, 64);
            q += __shfl_xor(q, d, 64);
        }
        if (lane == (unsigned)o) { mySum = v; mySq = q; }
    }
    if (lane < CO) {
        atomicAdd(&gsum[lane], mySum);
        atomicAdd(&gsq[lane], mySq);
    }
}

// ---------- kernel 4: per-channel scale/shift ----------
__global__ void finalize(const float* __restrict__ gsum, const float* __restrict__ gsq,
                         const float* __restrict__ gamma,
                         const float* __restrict__ beta,
                         float* __restrict__ scale, float* __restrict__ shift) {
    int o = threadIdx.x;
    if (o >= CO) return;
    float m   = gsum[o] / (float)H;
    float var = gsq[o] / (float)H - m * m;
    float inv = rsqrtf(var + BN_EPS);
    float sc  = gamma[o] * inv;
    scale[o] = sc;
    shift[o] = beta[o] - m * sc;
}

// ---------- kernel 5: apply BN in place over fp32 d_out (float4 per thread) ----------
__global__ __launch_bounds__(256) void bn_apply(float* __restrict__ out,
                                                const float* __restrict__ scale,
                                                const float* __restrict__ shift) {
    size_t t = (size_t)blockIdx.x * 256 + threadIdx.x;
    size_t base = t * 4;
    if (base >= (size_t)CO * H) return;
    int o = (int)(base / (size_t)H);     // H % 4 == 0 -> float4 never crosses channels
    float sc = scale[o], sh = shift[o];
    float4* p = reinterpret_cast<float4*>(out + base);
    float4 q = *p;
    q.x = q.x * sc + sh;
    q.y = q.y * sc + sh;
    q.z = q.z * sc + sh;
    q.w = q.w * sc + sh;
    *p = q;
}

// ---------- launch ----------
extern "C" void kernel_launch(void* const* d_in, const int* in_sizes, int n_in,
                              void* d_out, int out_size, void* d_ws, size_t ws_size,
                              hipStream_t stream) {
    const float* x     = (const float*)d_in[0];   // fp32 (1,CI,H,1)
    const float* w     = (const float*)d_in[1];   // fp32 (CO,CI,K)
    const float* gamma = (const float*)d_in[2];   // fp32 (CO)
    const float* beta  = (const float*)d_in[3];   // fp32 (CO)
    const int*   neigh = (const int*)d_in[4];     // int32 (H,K) — proven by R2/R3 identity
    float*       out   = (float*)d_out;           // fp32 (CO,H) — reference output dtype

    char* ws = (char*)d_ws;
    // ws layout
    const size_t XT_OFF    = 0;                     // H*CI*2      = 9,600,000 B
    const size_t WF_OFF    = 9600000;               // CO*CI*K*4   = 55,296 B
    const size_t STATS_OFF = 9655296;               // stats
    unsigned short* xT    = (unsigned short*)(ws + XT_OFF);
    float*          wf    = (float*)(ws + WF_OFF);
    float*          gsum  = (float*)(ws + STATS_OFF);
    float*          gsq   = (float*)(ws + STATS_OFF + 128);
    float*          scale = (float*)(ws + STATS_OFF + 256);
    float*          shift = (float*)(ws + STATS_OFF + 384);

    hipMemsetAsync(ws + STATS_OFF, 0, 512, stream);

    const int HB = (H + 255) / 256;                 // 1172
    prep_x<<<HB, 256, 0, stream>>>(x, xT);
    prep_w<<<1, 256, 0, stream>>>(w, wf);
    conv<<<HB, 256, 0, stream>>>(xT, wf, neigh, out, gsum, gsq);
    finalize<<<1, 64, 0, stream>>>(gsum, gsq, gamma, beta, scale, shift);

    const int NBN = (CO * H / 4 + 255) / 256;       // 9375
    bn_apply<<<NBN, 256, 0, stream>>>(out, scale, shift);
}